// Round 7
// baseline (8130.595 us; speedup 1.0000x reference)
//
#include <hip/hip_runtime.h>
#include <hip/hip_bf16.h>

// ---------------------------------------------------------------------------
// PredRNN (patched) — R7: one kernel per cell (phase A + neighbor-flag sync +
// phase B). Phase A: 7-wave stage-1 gate GEMMs + gate1 epilogue (R5 verbatim,
// o-preact kept in LDS). Sync: per-block release flag, wait on row neighbors
// r-1/r+1 only (they produce the memB halo). Phase B: 7-wave convO/convL
// K-split + gate2 (R5 verbatim). Block map b=blk&7,r=blk>>3 -> batch==XCD.
// ---------------------------------------------------------------------------

typedef __bf16 bf16x8 __attribute__((ext_vector_type(8)));
typedef float f32x4 __attribute__((ext_vector_type(4)));

namespace {
constexpr int  T     = 19;
constexpr int  INLEN = 10;

// workspace offsets (in floats)
constexpr long OFF_XPB   = 0;            // bf16 [8][10][1024][64]
constexpr long OFF_OUTSB = 2621440;      // bf16 [19][8][1024][64]
constexpr long OFF_HB    = 7602176;      // bf16 [4][8][1024][64]
constexpr long OFF_MB    = 8650752;      // bf16 2x [8][1024][64] (ping-pong)
constexpr long OFF_C     = 9175040;      // fp32 [4][8][64][1024]
constexpr long OFF_M     = 11272192;     // fp32 [8][64][1024]
constexpr long OFF_MEMB  = 11796480;     // bf16 [8][1024][128]
constexpr long OFF_WFA   = 12845056;     // bf16 4 x 516096
constexpr long OFF_WFB   = 13877248;     // bf16 4 x 81920
constexpr long OFF_WFD   = 14041088;     // bf16 36864
constexpr long OFF_BA    = 14059520;     // fp32 4 x 448
constexpr long OFF_FLG   = 14061312;     // 256 flags
constexpr long WS_NEEDED_FLOATS = 14061568;
}

__device__ __forceinline__ float sigf(float x)     { return 1.f / (1.f + __expf(-x)); }
__device__ __forceinline__ float tanhfast(float x) { return 2.f / (1.f + __expf(-2.f * x)) - 1.f; }
__device__ __forceinline__ unsigned short f2b(float f) {
  __hip_bfloat16 h = __float2bfloat16(f);
  return __builtin_bit_cast(unsigned short, h);
}
__device__ __forceinline__ f32x4 mfma16(bf16x8 a, bf16x8 b, f32x4 c) {
  return __builtin_amdgcn_mfma_f32_16x16x32_bf16(a, b, c, 0, 0, 0);
}

// ---------------------------------------------------------------------------
// kcell: grid 256 x 448 threads. blk -> (b = blk&7, r0 = blk>>3).
// NOTE: no __restrict__ on state buffers — in0 aliases hB/outsB.
// ---------------------------------------------------------------------------
__global__ __launch_bounds__(448) void kcell(
    const unsigned short* in0, long ibs,
    unsigned short* hBl,            // h of THIS layer: read in A, written in B
    const unsigned short* mBr, unsigned short* mBw,
    unsigned short* memB,
    const unsigned short* wAl, const unsigned short* wBl,
    const float* bAl, const float* bll,
    float* Cl, float* M,
    unsigned short* outsBt, int writeOuts,
    unsigned* flags, unsigned target)
{
  __shared__ __align__(16) char smem[65536];
  unsigned short* sIn = (unsigned short*)smem;
  float* sEx = (float*)smem;
  float* sOP = (float*)(smem + 57344);     // 2048 fp32, survives both phases

  const int blk = blockIdx.x;
  const int b = blk & 7, r0 = blk >> 3;
  const int tid = threadIdx.x;
  const int w = tid >> 6, lane = tid & 63, q = lane >> 4, n16 = lane & 15;

  // ================= phase A =================
  {
    const unsigned short* base0 = in0 + (long)b * ibs;
    const unsigned short* base1 = hBl + ((long)b << 16);
    const unsigned short* base2 = mBr + ((long)b << 16);
    for (int s = tid; s < 3 * 816; s += 448) {
      int inp = s / 816, rem = s - inp * 816;
      int slot = rem >> 3, cg = rem & 7;
      int rr = slot / 34, cl2 = slot - rr * 34;
      int gr = r0 - 1 + rr, gc = cl2 - 1;
      const unsigned short* bp = (inp == 0) ? base0 : ((inp == 1) ? base1 : base2);
      uint4 v = make_uint4(0u, 0u, 0u, 0u);
      if ((unsigned)gr < 32u && (unsigned)gc < 32u)
        v = *(const uint4*)(bp + ((long)(gr * 32 + gc) << 6) + cg * 8);
      *(uint4*)(sIn + inp * 6528 + slot * 64 + ((cg ^ (slot & 7)) * 8)) = v;
    }
    __syncthreads();

    f32x4 acc[4][2];
    #pragma unroll
    for (int i = 0; i < 4; ++i) {
      acc[i][0] = (f32x4){0.f,0.f,0.f,0.f};
      acc[i][1] = (f32x4){0.f,0.f,0.f,0.f};
    }
    const unsigned short* sb1 = sIn + ((w < 4) ? 6528 : 13056);
    const unsigned short* wbase = wAl + (long)w * 73728;

    #pragma unroll
    for (int p = 0; p < 2; ++p) {
      const unsigned short* sb = p ? sb1 : sIn;
      #pragma unroll
      for (int tap = 0; tap < 9; ++tap) {
        const int dy = tap / 3, dx = tap - dy * 3;
        #pragma unroll
        for (int cc = 0; cc < 2; ++cc) {
          const unsigned short* wp = wbase + (long)(((p * 9 + tap) * 2 + cc) * 4) * 512 + lane * 8;
          bf16x8 a0 = *(const bf16x8*)(wp);
          bf16x8 a1 = *(const bf16x8*)(wp + 512);
          bf16x8 a2 = *(const bf16x8*)(wp + 1024);
          bf16x8 a3 = *(const bf16x8*)(wp + 1536);
          const int g = cc * 4 + q;
          bf16x8 bf0, bf1;
          { int slot = dy * 34 + n16 + dx;
            bf0 = *(const bf16x8*)(sb + slot * 64 + ((g ^ (slot & 7)) * 8)); }
          { int slot = dy * 34 + 16 + n16 + dx;
            bf1 = *(const bf16x8*)(sb + slot * 64 + ((g ^ (slot & 7)) * 8)); }
          acc[0][0] = mfma16(a0, bf0, acc[0][0]); acc[0][1] = mfma16(a0, bf1, acc[0][1]);
          acc[1][0] = mfma16(a1, bf0, acc[1][0]); acc[1][1] = mfma16(a1, bf1, acc[1][1]);
          acc[2][0] = mfma16(a2, bf0, acc[2][0]); acc[2][1] = mfma16(a2, bf1, acc[2][1]);
          acc[3][0] = mfma16(a3, bf0, acc[3][0]); acc[3][1] = mfma16(a3, bf1, acc[3][1]);
        }
      }
    }

    __syncthreads();   // all waves done reading sIn before slab overwrite
    #pragma unroll
    for (int i = 0; i < 4; ++i)
      #pragma unroll
      for (int j = 0; j < 2; ++j)
        #pragma unroll
        for (int r = 0; r < 4; ++r)
          sEx[w * 2048 + (i * 16 + q * 4 + r) * 32 + (j * 16 + n16)] = acc[i][j][r];
    __syncthreads();

    for (int idx = tid; idx < 2048; idx += 448) {
      const int ch = idx >> 5, pxl = idx & 31;
      const int pxg = r0 * 32 + pxl;
      float iv = sEx[idx]         + bAl[ch];
      float fv = sEx[2048 + idx]  + bAl[64 + ch];
      float gv = sEx[4096 + idx]  + bAl[128 + ch];
      float ov = sEx[6144 + idx]  + bAl[192 + ch];
      float i2 = sEx[8192 + idx]  + bAl[256 + ch];
      float f2 = sEx[10240 + idx] + bAl[320 + ch];
      float g2 = sEx[12288 + idx] + bAl[384 + ch];
      const long cmo = ((long)b * 64 + ch) * 1024 + pxg;
      float cn = sigf(fv) * Cl[cmo] + sigf(iv) * tanhfast(gv);
      float mn = sigf(f2) * M[cmo] + sigf(i2) * tanhfast(g2);
      Cl[cmo] = cn; M[cmo] = mn;
      sOP[idx] = ov;                                   // o-preact stays in LDS
      const long mo = (long)b * 1024 + pxg;
      memB[mo * 128 + ch]      = f2b(cn);
      memB[mo * 128 + 64 + ch] = f2b(mn);
      mBw[mo * 64 + ch]        = f2b(mn);
    }
  }

  // ===== publish row r0; wait for memB halo rows r0-1, r0+1 =====
  __threadfence();            // each thread: drain own global writes (device scope)
  __syncthreads();
  if (tid == 0)
    __hip_atomic_store(flags + blk, target, __ATOMIC_RELEASE, __HIP_MEMORY_SCOPE_AGENT);
  if (tid == 0 && r0 > 0) {
    while (__hip_atomic_load(flags + blk - 8, __ATOMIC_ACQUIRE, __HIP_MEMORY_SCOPE_AGENT) < target)
      __builtin_amdgcn_s_sleep(1);
    __threadfence();
  }
  if (tid == 64 && r0 < 31) {
    while (__hip_atomic_load(flags + blk + 8, __ATOMIC_ACQUIRE, __HIP_MEMORY_SCOPE_AGENT) < target)
      __builtin_amdgcn_s_sleep(1);
    __threadfence();
  }
  __syncthreads();

  // ================= phase B =================
  {
    const unsigned short* bp = memB + ((long)b << 17);
    for (int s = tid; s < 1632; s += 448) {
      int slot = s >> 4, cg = s & 15;
      int rr = slot / 34, cl2 = slot - rr * 34;
      int gr = r0 - 1 + rr, gc = cl2 - 1;
      uint4 v = make_uint4(0u, 0u, 0u, 0u);
      if ((unsigned)gr < 32u && (unsigned)gc < 32u)
        v = *(const uint4*)(bp + ((long)(gr * 32 + gc) << 7) + cg * 8);
      *(uint4*)(sIn + slot * 128 + ((cg ^ (slot & 7)) * 8)) = v;
    }
    __syncthreads();

    f32x4 accA[4][2];
    #pragma unroll
    for (int f = 0; f < 4; ++f) {
      accA[f][0] = (f32x4){0.f,0.f,0.f,0.f};
      accA[f][1] = (f32x4){0.f,0.f,0.f,0.f};
    }
    if (w < 6) {
      #pragma unroll
      for (int k5 = 0; k5 < 6; ++k5) {
        const int s = w * 6 + k5;
        const int tap = s >> 2, cc = s & 3;
        const int dy = tap / 3, dx = tap - dy * 3;
        const unsigned short* wp = wBl + (long)s * 2048 + lane * 8;
        bf16x8 a0 = *(const bf16x8*)(wp);
        bf16x8 a1 = *(const bf16x8*)(wp + 512);
        bf16x8 a2 = *(const bf16x8*)(wp + 1024);
        bf16x8 a3 = *(const bf16x8*)(wp + 1536);
        const int g = cc * 4 + q;
        bf16x8 bf0, bf1;
        { int slot = dy * 34 + n16 + dx;
          bf0 = *(const bf16x8*)(sIn + slot * 128 + ((g ^ (slot & 7)) * 8)); }
        { int slot = dy * 34 + 16 + n16 + dx;
          bf1 = *(const bf16x8*)(sIn + slot * 128 + ((g ^ (slot & 7)) * 8)); }
        accA[0][0] = mfma16(a0, bf0, accA[0][0]); accA[0][1] = mfma16(a0, bf1, accA[0][1]);
        accA[1][0] = mfma16(a1, bf0, accA[1][0]); accA[1][1] = mfma16(a1, bf1, accA[1][1]);
        accA[2][0] = mfma16(a2, bf0, accA[2][0]); accA[2][1] = mfma16(a2, bf1, accA[2][1]);
        accA[3][0] = mfma16(a3, bf0, accA[3][0]); accA[3][1] = mfma16(a3, bf1, accA[3][1]);
      }
    } else {
      #pragma unroll
      for (int cc = 0; cc < 4; ++cc) {
        const int s = 36 + cc;
        const unsigned short* wp = wBl + (long)s * 2048 + lane * 8;
        bf16x8 a0 = *(const bf16x8*)(wp);
        bf16x8 a1 = *(const bf16x8*)(wp + 512);
        bf16x8 a2 = *(const bf16x8*)(wp + 1024);
        bf16x8 a3 = *(const bf16x8*)(wp + 1536);
        const int g = cc * 4 + q;
        bf16x8 bf0, bf1;
        { int slot = 34 + n16 + 1;
          bf0 = *(const bf16x8*)(sIn + slot * 128 + ((g ^ (slot & 7)) * 8)); }
        { int slot = 34 + 16 + n16 + 1;
          bf1 = *(const bf16x8*)(sIn + slot * 128 + ((g ^ (slot & 7)) * 8)); }
        accA[0][0] = mfma16(a0, bf0, accA[0][0]); accA[0][1] = mfma16(a0, bf1, accA[0][1]);
        accA[1][0] = mfma16(a1, bf0, accA[1][0]); accA[1][1] = mfma16(a1, bf1, accA[1][1]);
        accA[2][0] = mfma16(a2, bf0, accA[2][0]); accA[2][1] = mfma16(a2, bf1, accA[2][1]);
        accA[3][0] = mfma16(a3, bf0, accA[3][0]); accA[3][1] = mfma16(a3, bf1, accA[3][1]);
      }
    }
    __syncthreads();
    #pragma unroll
    for (int i = 0; i < 4; ++i)
      #pragma unroll
      for (int j = 0; j < 2; ++j)
        #pragma unroll
        for (int r = 0; r < 4; ++r)
          sEx[w * 2048 + (i * 16 + q * 4 + r) * 32 + (j * 16 + n16)] = accA[i][j][r];
    __syncthreads();

    for (int idx = tid; idx < 2048; idx += 448) {
      const int ch = idx >> 5, pxl = idx & 31;
      const int pxg = r0 * 32 + pxl;
      float o = sOP[idx];
      #pragma unroll
      for (int ww = 0; ww < 6; ++ww) o += sEx[ww * 2048 + idx];
      float lg = sEx[12288 + idx] + bll[ch];
      unsigned short hv = f2b(sigf(o) * tanhfast(lg));
      hBl[((long)b * 1024 + pxg) * 64 + ch] = hv;
      if (writeOuts) outsBt[((long)b * 1024 + pxg) * 64 + ch] = hv;
    }
  }
}

// ---------------------------------------------------------------------------
// Final conv machinery (verbatim R2/R3, proven correct)
// ---------------------------------------------------------------------------
__device__ __forceinline__ void conv3_acc(
    const unsigned short* __restrict__ ip, int ciStride, int ciOff,
    const unsigned short* __restrict__ wf, int ncc, int ccoff,
    unsigned short* sIn, f32x4 (&acc)[4][4])
{
  const int tid = threadIdx.x;
  const int r0  = (int)blockIdx.y * 8;
  for (int s = tid; s < 2720; s += 256) {
    int slot = s >> 3, cg = s & 7;
    int rr = slot / 34, cl = slot - rr * 34;
    int gr = r0 - 1 + rr, gc = cl - 1;
    uint4 v = make_uint4(0u, 0u, 0u, 0u);
    if ((unsigned)gr < 32u && (unsigned)gc < 32u)
      v = *(const uint4*)(ip + (long)(gr * 32 + gc) * ciStride + ciOff + cg * 8);
    *(uint4*)(sIn + slot * 64 + ((cg ^ (slot & 7)) * 8)) = v;
  }
  __syncthreads();
  const int lane = tid & 63, w = tid >> 6;
  const int q = lane >> 4, n16 = lane & 15;
  #pragma unroll
  for (int i = 0; i < 4; ++i)
    #pragma unroll
    for (int j = 0; j < 4; ++j)
      acc[i][j] = (f32x4){0.f, 0.f, 0.f, 0.f};
  #pragma unroll
  for (int tap = 0; tap < 9; ++tap) {
    const int dy = tap / 3, dx = tap - dy * 3;
    #pragma unroll
    for (int cc = 0; cc < 2; ++cc) {
      const unsigned short* wp = wf + (long)(tap * ncc + ccoff + cc) * 2048 + lane * 8;
      bf16x8 a0 = *(const bf16x8*)(wp);
      bf16x8 a1 = *(const bf16x8*)(wp + 512);
      bf16x8 a2 = *(const bf16x8*)(wp + 1024);
      bf16x8 a3 = *(const bf16x8*)(wp + 1536);
      const int cs = cc * 4 + q;
      bf16x8 bfr[4];
      #pragma unroll
      for (int pf = 0; pf < 4; ++pf) {
        int slot = (w * 2 + (pf >> 1) + dy) * 34 + (pf & 1) * 16 + dx + n16;
        bfr[pf] = *(const bf16x8*)(sIn + slot * 64 + ((cs ^ (slot & 7)) * 8));
      }
      #pragma unroll
      for (int j = 0; j < 4; ++j) {
        acc[0][j] = mfma16(a0, bfr[j], acc[0][j]);
        acc[1][j] = mfma16(a1, bfr[j], acc[1][j]);
        acc[2][j] = mfma16(a2, bfr[j], acc[2][j]);
        acc[3][j] = mfma16(a3, bfr[j], acc[3][j]);
      }
    }
  }
}

__global__ __launch_bounds__(256) void kconv_final(
    const unsigned short* __restrict__ outsB,
    const unsigned short* __restrict__ wdf, const float* __restrict__ bd,
    float* __restrict__ dout)
{
  __shared__ __align__(16) unsigned short sIn[21760];
  const int img = blockIdx.x;
  const int b = img / 19, t = img - b * 19;
  f32x4 acc[4][4];
  conv3_acc(outsB + ((long)t * 8 + b) * 65536, 64, 0, wdf, 2, 0, sIn, acc);
  const int tid = threadIdx.x;
  const int lane = tid & 63, w = tid >> 6;
  const int q = lane >> 4, n16 = lane & 15;
  const int r0 = (int)blockIdx.y * 8;
  float* ob = dout + (long)img * 65536;
  #pragma unroll
  for (int i = 0; i < 4; ++i) {
    #pragma unroll
    for (int r = 0; r < 4; ++r) {
      const int co = i * 16 + q * 4 + r;
      const float bv = bd[co];
      #pragma unroll
      for (int j = 0; j < 4; ++j) {
        int row = r0 + w * 2 + (j >> 1);
        int col = (j & 1) * 16 + n16;
        ob[((co >> 3) * 32 + row) * 256 + (co & 7) * 32 + col] = sigf(acc[i][j][r] + bv);
      }
    }
  }
}

// patch division -> bf16 channels-last [b*10+t][1024][64]; grid (80)
__global__ __launch_bounds__(256) void kpatch(const float* __restrict__ x,
                                              unsigned short* __restrict__ xpB)
{
  __shared__ __align__(16) unsigned short sT[2048];
  const int img = blockIdx.x, tid = threadIdx.x;
  const float* xi = x + (long)img * 65536;
  unsigned short* xo = xpB + (long)img * 65536;
  for (int p = 0; p < 32; ++p) {
    __syncthreads();
    int ch = tid >> 2, q0 = (tid & 3) * 8;
    const float* s = xi + ((ch >> 3) * 32 + p) * 256 + (ch & 7) * 32 + q0;
    float4 v0 = *(const float4*)s, v1 = *(const float4*)(s + 4);
    float vv[8] = {v0.x, v0.y, v0.z, v0.w, v1.x, v1.y, v1.z, v1.w};
    #pragma unroll
    for (int k = 0; k < 8; ++k) {
      int qq = q0 + k;
      sT[qq * 64 + (((ch >> 3) ^ (qq & 7)) * 8) + (ch & 7)] = f2b(vv[k]);
    }
    __syncthreads();
    int q = tid >> 3, cg = tid & 7;
    uint4 v = *(const uint4*)(sT + q * 64 + ((cg ^ (q & 7)) * 8));
    *(uint4*)(xo + (long)(p * 32 + q) * 64 + cg * 8) = v;
  }
}

// weight fragment packer (used for Wd only)
__global__ __launch_bounds__(256) void kprepw(const float* __restrict__ src,
                                              unsigned short* __restrict__ dst,
                                              int Cout, int Cin, int KK)
{
  long n = (long)Cout * Cin * KK;
  long idx = (long)blockIdx.x * 256 + threadIdx.x;
  if (idx >= n) return;
  int ncc = Cin >> 5;
  long tmp = idx >> 3; int e = (int)(idx & 7);
  int lane = (int)(tmp & 63); tmp >>= 6;
  int cf = (int)(tmp & 3); tmp >>= 2;
  int cc = (int)(tmp % ncc); tmp /= ncc;
  int tap = (int)(tmp % KK); int chunk = (int)(tmp / KK);
  int co = chunk * 64 + cf * 16 + (lane & 15);
  int ci = cc * 32 + (lane >> 4) * 8 + e;
  dst[idx] = f2b(src[((long)co * Cin + ci) * KK + tap]);
}

// pack fused stage-1 weights (R3 layout): [l][w][p][tap][cc][frag][lane][8]
__global__ __launch_bounds__(256) void kpackA(
    const float* __restrict__ Wx, const float* __restrict__ Wh,
    const float* __restrict__ Wm, unsigned short* __restrict__ wfA)
{
  long idx = (long)blockIdx.x * 256 + threadIdx.x;
  if (idx >= 2064384) return;
  int e = (int)(idx & 7);
  long t = idx >> 3;
  int lane = (int)(t & 63); t >>= 6;
  int frag = (int)(t & 3);  t >>= 2;
  int cc   = (int)(t & 1);  t >>= 1;
  int tap  = (int)(t % 9);  t /= 9;
  int p    = (int)(t & 1);  t >>= 1;
  int w    = (int)(t % 7);
  int l    = (int)(t / 7);
  int co = frag * 16 + (lane & 15);
  int ci = cc * 32 + (lane >> 4) * 8 + e;
  const float* src; int row;
  if (w < 4) {
    if (p == 0) { src = Wx + (long)l * 258048; row = (w == 3 ? 384 : w * 64) + co; }
    else        { src = Wh + (long)l * 147456; row = (w == 3 ? 192 : w * 64) + co; }
  } else {
    if (p == 0) { src = Wx + (long)l * 258048; row = 192 + (w - 4) * 64 + co; }
    else        { src = Wm + (long)l * 110592; row = (w - 4) * 64 + co; }
  }
  wfA[idx] = f2b(src[((long)row * 64 + ci) * 9 + tap]);
}

// pack convO/convL step-ordered weights (R3 layout): [l][s 0..39][frag][lane][8]
__global__ __launch_bounds__(256) void kpackB(
    const float* __restrict__ Wo, const float* __restrict__ Wl,
    unsigned short* __restrict__ wfB)
{
  long idx = (long)blockIdx.x * 256 + threadIdx.x;
  if (idx >= 327680) return;
  int e = (int)(idx & 7);
  long t = idx >> 3;
  int lane = (int)(t & 63); t >>= 6;
  int frag = (int)(t & 3);  t >>= 2;
  int s    = (int)(t % 40);
  int l    = (int)(t / 40);
  int co = frag * 16 + (lane & 15);
  float v;
  if (s < 36) {
    int tap = s >> 2, cc = s & 3;
    int ci = cc * 32 + (lane >> 4) * 8 + e;
    v = Wo[(long)l * 73728 + ((long)co * 128 + ci) * 9 + tap];
  } else {
    int cc = s - 36;
    int ci = cc * 32 + (lane >> 4) * 8 + e;
    v = Wl[(long)l * 8192 + (long)co * 128 + ci];
  }
  wfB[idx] = f2b(v);
}

// pre-summed gate biases: [l][slot i,f,g,o(+bo),i2,f2,g2][64]
__global__ __launch_bounds__(256) void kpackbA(
    const float* __restrict__ bx, const float* __restrict__ bh,
    const float* __restrict__ bm, const float* __restrict__ bo,
    float* __restrict__ bA)
{
  int idx = blockIdx.x * 256 + threadIdx.x;
  if (idx >= 1792) return;
  int ch = idx & 63, w = (idx >> 6) % 7, l = (idx >> 6) / 7;
  const float* bxl = bx + l * 448;
  const float* bhl = bh + l * 256;
  const float* bml = bm + l * 192;
  const float* bol = bo + l * 64;
  float v;
  if (w < 3)       v = bxl[w * 64 + ch] + bhl[w * 64 + ch];
  else if (w == 3) v = bxl[384 + ch] + bhl[192 + ch] + bol[ch];
  else             v = bxl[192 + (w - 4) * 64 + ch] + bml[(w - 4) * 64 + ch];
  bA[idx] = v;
}

extern "C" void kernel_launch(void* const* d_in, const int* in_sizes, int n_in,
                              void* d_out, int out_size, void* d_ws, size_t ws_size,
                              hipStream_t stream)
{
  (void)in_sizes; (void)n_in; (void)out_size;
  if (ws_size < WS_NEEDED_FLOATS * sizeof(float)) return;

  const float* x  = (const float*)d_in[0];
  const float* Wx = (const float*)d_in[3];
  const float* bx = (const float*)d_in[4];
  const float* Wh = (const float*)d_in[5];
  const float* bh = (const float*)d_in[6];
  const float* Wm = (const float*)d_in[7];
  const float* bm = (const float*)d_in[8];
  const float* Wo = (const float*)d_in[9];
  const float* bo = (const float*)d_in[10];
  const float* Wl = (const float*)d_in[11];
  const float* bl = (const float*)d_in[12];
  const float* Wd = (const float*)d_in[13];
  const float* bd = (const float*)d_in[14];
  float* ws  = (float*)d_ws;
  float* out = (float*)d_out;

  unsigned short* xpB   = (unsigned short*)(ws + OFF_XPB);
  unsigned short* outsB = (unsigned short*)(ws + OFF_OUTSB);
  unsigned short* hB    = (unsigned short*)(ws + OFF_HB);
  unsigned short* mB0   = (unsigned short*)(ws + OFF_MB);
  unsigned short* mB1   = mB0 + 524288;
  float*          C     = ws + OFF_C;
  float*          M     = ws + OFF_M;
  unsigned short* memB  = (unsigned short*)(ws + OFF_MEMB);
  unsigned short* wfA   = (unsigned short*)(ws + OFF_WFA);
  unsigned short* wfB   = (unsigned short*)(ws + OFF_WFB);
  unsigned short* wfD   = (unsigned short*)(ws + OFF_WFD);
  float*          bA    = ws + OFF_BA;
  unsigned*       flags = (unsigned*)(ws + OFF_FLG);

  kpackA<<<dim3(8064), 256, 0, stream>>>(Wx, Wh, Wm, wfA);
  kpackB<<<dim3(1280), 256, 0, stream>>>(Wo, Wl, wfB);
  kpackbA<<<dim3(7), 256, 0, stream>>>(bx, bh, bm, bo, bA);
  kprepw<<<dim3(144), 256, 0, stream>>>(Wd, wfD, 64, 64, 9);
  kpatch<<<dim3(80), 256, 0, stream>>>(x, xpB);
  // zero h, m(bf16 x2), C, M (contiguous region) + flags
  hipMemsetAsync(ws + OFF_HB, 0, (OFF_MEMB - OFF_HB) * sizeof(float), stream);
  hipMemsetAsync(flags, 0, 256 * sizeof(unsigned), stream);

  for (int t = 0; t < T; ++t) {
    for (int l = 0; l < 4; ++l) {
      const int cell = t * 4 + l;
      const unsigned short* in0; long ibs;
      if (l == 0) {
        if (t < INLEN) { in0 = xpB + (long)t * 65536; ibs = 655360; }
        else           { in0 = outsB + (long)(t - 1) * 524288; ibs = 65536; }
      } else {
        in0 = hB + (long)(l - 1) * 524288; ibs = 65536;
      }
      const unsigned short* mBr = (cell & 1) ? mB1 : mB0;
      unsigned short*       mBw = (cell & 1) ? mB0 : mB1;
      kcell<<<dim3(256), 448, 0, stream>>>(
          in0, ibs, hB + (long)l * 524288, mBr, mBw, memB,
          wfA + (long)l * 516096, wfB + (long)l * 81920,
          bA + l * 448, bl + l * 64,
          C + (long)l * 524288, M,
          outsB + (long)t * 524288, (l == 3) ? 1 : 0,
          flags, (unsigned)(cell + 1));
    }
  }
  kconv_final<<<dim3(152, 4), 256, 0, stream>>>(outsB, wfD, bd, out);
}

// Round 8
// 3509.573 us; speedup vs baseline: 2.3167x; 2.3167x over previous
//
#include <hip/hip_runtime.h>
#include <hip/hip_bf16.h>

// ---------------------------------------------------------------------------
// PredRNN (patched) — R8: ONE kernel per cell, halo-recompute, no cross-block
// sync. Each block (b, row r0): phase A computes gate GEMMs for rows
// r0-1..r0+1 (3-row acc; A-frags amortized 3x), writes bf16 c/m mem tile to
// LDS (sInB) for all 3 rows, global state for own row only. Phase B
// (convO/convL + gate2) then runs entirely from LDS. State races avoided via
// parity ping-pong (C,h by t; M,mB by cell). 76 cell dispatches total.
// ---------------------------------------------------------------------------

typedef __bf16 bf16x8 __attribute__((ext_vector_type(8)));
typedef float f32x4 __attribute__((ext_vector_type(4)));

namespace {
constexpr int  T     = 19;
constexpr int  INLEN = 10;

// workspace offsets (in floats)
constexpr long OFF_XPB   = 0;            // bf16 [8][10][1024][64]
constexpr long OFF_OUTSB = 2621440;      // bf16 [19][8][1024][64]
constexpr long OFF_HB    = 7602176;      // bf16 [2][4][8][1024][64]
constexpr long OFF_MB    = 9699328;      // bf16 [2][8][1024][64]
constexpr long OFF_C     = 10223616;     // fp32 [2][4][8][64][1024]
constexpr long OFF_M     = 14417920;     // fp32 [2][8][64][1024]
constexpr long OFF_WFA   = 15466496;     // bf16 4 x 516096
constexpr long OFF_WFB   = 16498688;     // bf16 4 x 81920
constexpr long OFF_WFD   = 16662528;     // bf16 36864
constexpr long OFF_BA    = 16680960;     // fp32 4 x 448
constexpr long WS_NEEDED_FLOATS = 16682752;

// LDS layout (bytes)
constexpr int LDS_INA  = 0;        // 3 strips x 170 slots x 64ch x 2B = 65280
constexpr int LDS_EXA  = 65280;    // 3 slabs x 2048 fp32 = 24576
constexpr int LDS_INB  = 89856;    // 102 slots x 128ch x 2B = 26112
constexpr int LDS_OP   = 115968;   // 2048 fp32 = 8192
constexpr int LDS_TOT  = 124160;
// phase B exchange (7 x 2048 fp32 = 57344) reuses LDS_INA region
}

__device__ __forceinline__ float sigf(float x)     { return 1.f / (1.f + __expf(-x)); }
__device__ __forceinline__ float tanhfast(float x) { return 2.f / (1.f + __expf(-2.f * x)) - 1.f; }
__device__ __forceinline__ unsigned short f2b(float f) {
  __hip_bfloat16 h = __float2bfloat16(f);
  return __builtin_bit_cast(unsigned short, h);
}
__device__ __forceinline__ f32x4 mfma16(bf16x8 a, bf16x8 b, f32x4 c) {
  return __builtin_amdgcn_mfma_f32_16x16x32_bf16(a, b, c, 0, 0, 0);
}

// ---------------------------------------------------------------------------
// kcell: grid 256 x 448 threads (7 waves). blk -> (b = blk&7, r0 = blk>>3).
// ---------------------------------------------------------------------------
__global__ __launch_bounds__(448, 1) void kcell(
    const unsigned short* in0, long ibs,
    const unsigned short* hRead, unsigned short* hWrite,
    const unsigned short* mBr, unsigned short* mBw,
    const float* Cprev, float* Cnext,
    const float* Mprev, float* Mnext,
    const unsigned short* wAl, const unsigned short* wBl,
    const float* bAl, const float* bll,
    unsigned short* outsBt, int writeOuts)
{
  __shared__ __align__(16) char smem[LDS_TOT];
  unsigned short* sInA = (unsigned short*)(smem + LDS_INA);
  float*          sExA = (float*)(smem + LDS_EXA);
  unsigned short* sInB = (unsigned short*)(smem + LDS_INB);
  float*          sOP  = (float*)(smem + LDS_OP);
  float*          sExB = (float*)smem;                 // reuses sInA region

  const int blk = blockIdx.x;
  const int b = blk & 7, r0 = blk >> 3;
  const int tid = threadIdx.x;
  const int w = tid >> 6, lane = tid & 63, q = lane >> 4, n16 = lane & 15;

  // ---- stage 3 input strips: rows r0-2..r0+2, cols -1..32, 64ch swizzled ---
  {
    const unsigned short* base0 = in0 + (long)b * ibs;
    const unsigned short* base1 = hRead + ((long)b << 16);
    const unsigned short* base2 = mBr + ((long)b << 16);
    for (int s = tid; s < 4080; s += 448) {
      int inp = s / 1360, rem = s - inp * 1360;
      int slot = rem >> 3, cg = rem & 7;
      int rr = slot / 34, cl = slot - rr * 34;
      int gr = r0 - 2 + rr, gc = cl - 1;
      const unsigned short* bp = (inp == 0) ? base0 : ((inp == 1) ? base1 : base2);
      uint4 v = make_uint4(0u, 0u, 0u, 0u);
      if ((unsigned)gr < 32u && (unsigned)gc < 32u)
        v = *(const uint4*)(bp + ((long)(gr * 32 + gc) << 6) + cg * 8);
      *(uint4*)(sInA + inp * 10880 + slot * 64 + ((cg ^ (slot & 7)) * 8)) = v;
    }
  }
  __syncthreads();

  // ---- phase A K-loop: 3-row accumulator ----------------------------------
  f32x4 acc[4][2][3];   // [cofrag][colgroup][pass row]
  #pragma unroll
  for (int i = 0; i < 4; ++i)
    #pragma unroll
    for (int cg = 0; cg < 2; ++cg)
      #pragma unroll
      for (int k = 0; k < 3; ++k)
        acc[i][cg][k] = (f32x4){0.f, 0.f, 0.f, 0.f};

  {
    const unsigned short* wbase = wAl + (long)w * 73728;
    const unsigned short* sb1 = sInA + ((w < 4) ? 10880 : 21760);
    #pragma unroll
    for (int sec = 0; sec < 2; ++sec) {
      const unsigned short* sb = sec ? sb1 : sInA;
      #pragma unroll
      for (int tap = 0; tap < 9; ++tap) {
        const int dy = tap / 3, dx = tap - dy * 3;
        #pragma unroll
        for (int cc = 0; cc < 2; ++cc) {
          const unsigned short* wp =
              wbase + (long)(((sec * 9 + tap) * 2 + cc) * 4) * 512 + lane * 8;
          bf16x8 a0 = *(const bf16x8*)(wp);
          bf16x8 a1 = *(const bf16x8*)(wp + 512);
          bf16x8 a2 = *(const bf16x8*)(wp + 1024);
          bf16x8 a3 = *(const bf16x8*)(wp + 1536);
          const int g = cc * 4 + q;
          bf16x8 B[2][3];
          #pragma unroll
          for (int cg = 0; cg < 2; ++cg)
            #pragma unroll
            for (int k = 0; k < 3; ++k) {
              const int slot = (dy + k) * 34 + cg * 16 + dx + n16;
              B[cg][k] = *(const bf16x8*)(sb + slot * 64 + ((g ^ (slot & 7)) * 8));
            }
          #pragma unroll
          for (int cg = 0; cg < 2; ++cg)
            #pragma unroll
            for (int k = 0; k < 3; ++k) {
              acc[0][cg][k] = mfma16(a0, B[cg][k], acc[0][cg][k]);
              acc[1][cg][k] = mfma16(a1, B[cg][k], acc[1][cg][k]);
              acc[2][cg][k] = mfma16(a2, B[cg][k], acc[2][cg][k]);
              acc[3][cg][k] = mfma16(a3, B[cg][k], acc[3][cg][k]);
            }
        }
      }
    }
  }

  // ---- gate1 epilogue: 3 passes (rows r0-1, r0, r0+1) ---------------------
  #pragma unroll
  for (int p = 0; p < 3; ++p) {
    const int row = r0 - 1 + p;
    const bool inb = (unsigned)row < 32u;
    __syncthreads();   // slabs free (prev pass m-epilogue done)
    if (w < 3) {       // gates i,f,g -> slabs 0..2
      #pragma unroll
      for (int i = 0; i < 4; ++i)
        #pragma unroll
        for (int cg = 0; cg < 2; ++cg)
          #pragma unroll
          for (int r = 0; r < 4; ++r)
            sExA[w * 2048 + (i * 16 + q * 4 + r) * 32 + cg * 16 + n16] = acc[i][cg][p][r];
    } else if (w == 3 && p == 1) {   // gate o: own row -> sOP (+bias)
      #pragma unroll
      for (int i = 0; i < 4; ++i)
        #pragma unroll
        for (int cg = 0; cg < 2; ++cg)
          #pragma unroll
          for (int r = 0; r < 4; ++r) {
            const int co = i * 16 + q * 4 + r;
            sOP[co * 32 + cg * 16 + n16] = acc[i][cg][1][r] + bAl[192 + co];
          }
    }
    __syncthreads();
    // c-epilogue
    for (int idx = tid; idx < 2048; idx += 448) {
      const int ch = idx >> 5, px = idx & 31;
      const int slot = p * 34 + px + 1;
      unsigned short* dst = sInB + slot * 128 + (((ch >> 3) ^ (slot & 7)) * 8) + (ch & 7);
      if (inb) {
        const float iv = sExA[idx]        + bAl[ch];
        const float fv = sExA[2048 + idx] + bAl[64 + ch];
        const float gv = sExA[4096 + idx] + bAl[128 + ch];
        const long cmo = ((long)b * 64 + ch) * 1024 + row * 32 + px;
        const float cn = sigf(fv) * Cprev[cmo] + sigf(iv) * tanhfast(gv);
        if (p == 1) Cnext[cmo] = cn;
        *dst = f2b(cn);
      } else *dst = 0;
    }
    __syncthreads();
    if (w >= 4) {      // gates i',f',g' -> slabs 0..2
      #pragma unroll
      for (int i = 0; i < 4; ++i)
        #pragma unroll
        for (int cg = 0; cg < 2; ++cg)
          #pragma unroll
          for (int r = 0; r < 4; ++r)
            sExA[(w - 4) * 2048 + (i * 16 + q * 4 + r) * 32 + cg * 16 + n16] = acc[i][cg][p][r];
    }
    __syncthreads();
    // m-epilogue
    for (int idx = tid; idx < 2048; idx += 448) {
      const int ch = idx >> 5, px = idx & 31;
      const int slot = p * 34 + px + 1;
      const int grp = 8 + (ch >> 3);
      unsigned short* dst = sInB + slot * 128 + ((grp ^ (slot & 7)) * 8) + (ch & 7);
      if (inb) {
        const float iv = sExA[idx]        + bAl[256 + ch];
        const float fv = sExA[2048 + idx] + bAl[320 + ch];
        const float gv = sExA[4096 + idx] + bAl[384 + ch];
        const long cmo = ((long)b * 64 + ch) * 1024 + row * 32 + px;
        const float mn = sigf(fv) * Mprev[cmo] + sigf(iv) * tanhfast(gv);
        const unsigned short mb = f2b(mn);
        if (p == 1) {
          Mnext[cmo] = mn;
          mBw[((long)b * 1024 + row * 32 + px) * 64 + ch] = mb;
        }
        *dst = mb;
      } else *dst = 0;
    }
  }
  __syncthreads();   // sInB complete

  // ---- phase B: convO (6 waves x 6 steps) + convL (wave 6), from LDS ------
  f32x4 accB[4][2];
  #pragma unroll
  for (int f = 0; f < 4; ++f) {
    accB[f][0] = (f32x4){0.f,0.f,0.f,0.f};
    accB[f][1] = (f32x4){0.f,0.f,0.f,0.f};
  }
  if (w < 6) {
    #pragma unroll
    for (int k5 = 0; k5 < 6; ++k5) {
      const int s = w * 6 + k5;
      const int tap = s >> 2, cc = s & 3;
      const int dy = tap / 3, dx = tap - dy * 3;
      const unsigned short* wp = wBl + (long)s * 2048 + lane * 8;
      bf16x8 a0 = *(const bf16x8*)(wp);
      bf16x8 a1 = *(const bf16x8*)(wp + 512);
      bf16x8 a2 = *(const bf16x8*)(wp + 1024);
      bf16x8 a3 = *(const bf16x8*)(wp + 1536);
      const int g = cc * 4 + q;
      bf16x8 bf0, bf1;
      { int slot = dy * 34 + n16 + dx;
        bf0 = *(const bf16x8*)(sInB + slot * 128 + ((g ^ (slot & 7)) * 8)); }
      { int slot = dy * 34 + 16 + n16 + dx;
        bf1 = *(const bf16x8*)(sInB + slot * 128 + ((g ^ (slot & 7)) * 8)); }
      accB[0][0] = mfma16(a0, bf0, accB[0][0]); accB[0][1] = mfma16(a0, bf1, accB[0][1]);
      accB[1][0] = mfma16(a1, bf0, accB[1][0]); accB[1][1] = mfma16(a1, bf1, accB[1][1]);
      accB[2][0] = mfma16(a2, bf0, accB[2][0]); accB[2][1] = mfma16(a2, bf1, accB[2][1]);
      accB[3][0] = mfma16(a3, bf0, accB[3][0]); accB[3][1] = mfma16(a3, bf1, accB[3][1]);
    }
  } else {
    #pragma unroll
    for (int cc = 0; cc < 4; ++cc) {
      const int s = 36 + cc;
      const unsigned short* wp = wBl + (long)s * 2048 + lane * 8;
      bf16x8 a0 = *(const bf16x8*)(wp);
      bf16x8 a1 = *(const bf16x8*)(wp + 512);
      bf16x8 a2 = *(const bf16x8*)(wp + 1024);
      bf16x8 a3 = *(const bf16x8*)(wp + 1536);
      const int g = cc * 4 + q;
      bf16x8 bf0, bf1;
      { int slot = 34 + n16 + 1;
        bf0 = *(const bf16x8*)(sInB + slot * 128 + ((g ^ (slot & 7)) * 8)); }
      { int slot = 34 + 16 + n16 + 1;
        bf1 = *(const bf16x8*)(sInB + slot * 128 + ((g ^ (slot & 7)) * 8)); }
      accB[0][0] = mfma16(a0, bf0, accB[0][0]); accB[0][1] = mfma16(a0, bf1, accB[0][1]);
      accB[1][0] = mfma16(a1, bf0, accB[1][0]); accB[1][1] = mfma16(a1, bf1, accB[1][1]);
      accB[2][0] = mfma16(a2, bf0, accB[2][0]); accB[2][1] = mfma16(a2, bf1, accB[2][1]);
      accB[3][0] = mfma16(a3, bf0, accB[3][0]); accB[3][1] = mfma16(a3, bf1, accB[3][1]);
    }
  }
  // exchange into sExB (reuses sInA region; sInA dead since phase A K-loop)
  #pragma unroll
  for (int i = 0; i < 4; ++i)
    #pragma unroll
    for (int cg = 0; cg < 2; ++cg)
      #pragma unroll
      for (int r = 0; r < 4; ++r)
        sExB[w * 2048 + (i * 16 + q * 4 + r) * 32 + cg * 16 + n16] = accB[i][cg][r];
  __syncthreads();

  // gate2 epilogue: h = sig(o)*tanh(l), own row
  for (int idx = tid; idx < 2048; idx += 448) {
    const int ch = idx >> 5, px = idx & 31;
    const int pxg = r0 * 32 + px;
    float o = sOP[idx];
    #pragma unroll
    for (int ww = 0; ww < 6; ++ww) o += sExB[ww * 2048 + idx];
    const float lg = sExB[12288 + idx] + bll[ch];
    const unsigned short hv = f2b(sigf(o) * tanhfast(lg));
    hWrite[((long)b * 1024 + pxg) * 64 + ch] = hv;
    if (writeOuts) outsBt[((long)b * 1024 + pxg) * 64 + ch] = hv;
  }
}

// ---------------------------------------------------------------------------
// Final conv machinery (verbatim R2/R3, proven correct)
// ---------------------------------------------------------------------------
__device__ __forceinline__ void conv3_acc(
    const unsigned short* __restrict__ ip, int ciStride, int ciOff,
    const unsigned short* __restrict__ wf, int ncc, int ccoff,
    unsigned short* sIn, f32x4 (&acc)[4][4])
{
  const int tid = threadIdx.x;
  const int r0  = (int)blockIdx.y * 8;
  for (int s = tid; s < 2720; s += 256) {
    int slot = s >> 3, cg = s & 7;
    int rr = slot / 34, cl = slot - rr * 34;
    int gr = r0 - 1 + rr, gc = cl - 1;
    uint4 v = make_uint4(0u, 0u, 0u, 0u);
    if ((unsigned)gr < 32u && (unsigned)gc < 32u)
      v = *(const uint4*)(ip + (long)(gr * 32 + gc) * ciStride + ciOff + cg * 8);
    *(uint4*)(sIn + slot * 64 + ((cg ^ (slot & 7)) * 8)) = v;
  }
  __syncthreads();
  const int lane = tid & 63, w = tid >> 6;
  const int q = lane >> 4, n16 = lane & 15;
  #pragma unroll
  for (int i = 0; i < 4; ++i)
    #pragma unroll
    for (int j = 0; j < 4; ++j)
      acc[i][j] = (f32x4){0.f, 0.f, 0.f, 0.f};
  #pragma unroll
  for (int tap = 0; tap < 9; ++tap) {
    const int dy = tap / 3, dx = tap - dy * 3;
    #pragma unroll
    for (int cc = 0; cc < 2; ++cc) {
      const unsigned short* wp = wf + (long)(tap * ncc + ccoff + cc) * 2048 + lane * 8;
      bf16x8 a0 = *(const bf16x8*)(wp);
      bf16x8 a1 = *(const bf16x8*)(wp + 512);
      bf16x8 a2 = *(const bf16x8*)(wp + 1024);
      bf16x8 a3 = *(const bf16x8*)(wp + 1536);
      const int cs = cc * 4 + q;
      bf16x8 bfr[4];
      #pragma unroll
      for (int pf = 0; pf < 4; ++pf) {
        int slot = (w * 2 + (pf >> 1) + dy) * 34 + (pf & 1) * 16 + dx + n16;
        bfr[pf] = *(const bf16x8*)(sIn + slot * 64 + ((cs ^ (slot & 7)) * 8));
      }
      #pragma unroll
      for (int j = 0; j < 4; ++j) {
        acc[0][j] = mfma16(a0, bfr[j], acc[0][j]);
        acc[1][j] = mfma16(a1, bfr[j], acc[1][j]);
        acc[2][j] = mfma16(a2, bfr[j], acc[2][j]);
        acc[3][j] = mfma16(a3, bfr[j], acc[3][j]);
      }
    }
  }
}

__global__ __launch_bounds__(256) void kconv_final(
    const unsigned short* __restrict__ outsB,
    const unsigned short* __restrict__ wdf, const float* __restrict__ bd,
    float* __restrict__ dout)
{
  __shared__ __align__(16) unsigned short sIn[21760];
  const int img = blockIdx.x;
  const int b = img / 19, t = img - b * 19;
  f32x4 acc[4][4];
  conv3_acc(outsB + ((long)t * 8 + b) * 65536, 64, 0, wdf, 2, 0, sIn, acc);
  const int tid = threadIdx.x;
  const int lane = tid & 63, w = tid >> 6;
  const int q = lane >> 4, n16 = lane & 15;
  const int r0 = (int)blockIdx.y * 8;
  float* ob = dout + (long)img * 65536;
  #pragma unroll
  for (int i = 0; i < 4; ++i) {
    #pragma unroll
    for (int r = 0; r < 4; ++r) {
      const int co = i * 16 + q * 4 + r;
      const float bv = bd[co];
      #pragma unroll
      for (int j = 0; j < 4; ++j) {
        int row = r0 + w * 2 + (j >> 1);
        int col = (j & 1) * 16 + n16;
        ob[((co >> 3) * 32 + row) * 256 + (co & 7) * 32 + col] = sigf(acc[i][j][r] + bv);
      }
    }
  }
}

// patch division -> bf16 channels-last [b*10+t][1024][64]; grid (80)
__global__ __launch_bounds__(256) void kpatch(const float* __restrict__ x,
                                              unsigned short* __restrict__ xpB)
{
  __shared__ __align__(16) unsigned short sT[2048];
  const int img = blockIdx.x, tid = threadIdx.x;
  const float* xi = x + (long)img * 65536;
  unsigned short* xo = xpB + (long)img * 65536;
  for (int p = 0; p < 32; ++p) {
    __syncthreads();
    int ch = tid >> 2, q0 = (tid & 3) * 8;
    const float* s = xi + ((ch >> 3) * 32 + p) * 256 + (ch & 7) * 32 + q0;
    float4 v0 = *(const float4*)s, v1 = *(const float4*)(s + 4);
    float vv[8] = {v0.x, v0.y, v0.z, v0.w, v1.x, v1.y, v1.z, v1.w};
    #pragma unroll
    for (int k = 0; k < 8; ++k) {
      int qq = q0 + k;
      sT[qq * 64 + (((ch >> 3) ^ (qq & 7)) * 8) + (ch & 7)] = f2b(vv[k]);
    }
    __syncthreads();
    int q = tid >> 3, cg = tid & 7;
    uint4 v = *(const uint4*)(sT + q * 64 + ((cg ^ (q & 7)) * 8));
    *(uint4*)(xo + (long)(p * 32 + q) * 64 + cg * 8) = v;
  }
}

// weight fragment packer (used for Wd only)
__global__ __launch_bounds__(256) void kprepw(const float* __restrict__ src,
                                              unsigned short* __restrict__ dst,
                                              int Cout, int Cin, int KK)
{
  long n = (long)Cout * Cin * KK;
  long idx = (long)blockIdx.x * 256 + threadIdx.x;
  if (idx >= n) return;
  int ncc = Cin >> 5;
  long tmp = idx >> 3; int e = (int)(idx & 7);
  int lane = (int)(tmp & 63); tmp >>= 6;
  int cf = (int)(tmp & 3); tmp >>= 2;
  int cc = (int)(tmp % ncc); tmp /= ncc;
  int tap = (int)(tmp % KK); int chunk = (int)(tmp / KK);
  int co = chunk * 64 + cf * 16 + (lane & 15);
  int ci = cc * 32 + (lane >> 4) * 8 + e;
  dst[idx] = f2b(src[((long)co * Cin + ci) * KK + tap]);
}

// pack fused stage-1 weights (R3 layout): [l][w][sec][tap][cc][frag][lane][8]
__global__ __launch_bounds__(256) void kpackA(
    const float* __restrict__ Wx, const float* __restrict__ Wh,
    const float* __restrict__ Wm, unsigned short* __restrict__ wfA)
{
  long idx = (long)blockIdx.x * 256 + threadIdx.x;
  if (idx >= 2064384) return;
  int e = (int)(idx & 7);
  long t = idx >> 3;
  int lane = (int)(t & 63); t >>= 6;
  int frag = (int)(t & 3);  t >>= 2;
  int cc   = (int)(t & 1);  t >>= 1;
  int tap  = (int)(t % 9);  t /= 9;
  int p    = (int)(t & 1);  t >>= 1;
  int w    = (int)(t % 7);
  int l    = (int)(t / 7);
  int co = frag * 16 + (lane & 15);
  int ci = cc * 32 + (lane >> 4) * 8 + e;
  const float* src; int row;
  if (w < 4) {
    if (p == 0) { src = Wx + (long)l * 258048; row = (w == 3 ? 384 : w * 64) + co; }
    else        { src = Wh + (long)l * 147456; row = (w == 3 ? 192 : w * 64) + co; }
  } else {
    if (p == 0) { src = Wx + (long)l * 258048; row = 192 + (w - 4) * 64 + co; }
    else        { src = Wm + (long)l * 110592; row = (w - 4) * 64 + co; }
  }
  wfA[idx] = f2b(src[((long)row * 64 + ci) * 9 + tap]);
}

// pack convO/convL step-ordered weights (R3 layout): [l][s 0..39][frag][lane][8]
__global__ __launch_bounds__(256) void kpackB(
    const float* __restrict__ Wo, const float* __restrict__ Wl,
    unsigned short* __restrict__ wfB)
{
  long idx = (long)blockIdx.x * 256 + threadIdx.x;
  if (idx >= 327680) return;
  int e = (int)(idx & 7);
  long t = idx >> 3;
  int lane = (int)(t & 63); t >>= 6;
  int frag = (int)(t & 3);  t >>= 2;
  int s    = (int)(t % 40);
  int l    = (int)(t / 40);
  int co = frag * 16 + (lane & 15);
  float v;
  if (s < 36) {
    int tap = s >> 2, cc = s & 3;
    int ci = cc * 32 + (lane >> 4) * 8 + e;
    v = Wo[(long)l * 73728 + ((long)co * 128 + ci) * 9 + tap];
  } else {
    int cc = s - 36;
    int ci = cc * 32 + (lane >> 4) * 8 + e;
    v = Wl[(long)l * 8192 + (long)co * 128 + ci];
  }
  wfB[idx] = f2b(v);
}

// pre-summed gate biases: [l][slot i,f,g,o(+bo),i2,f2,g2][64]
__global__ __launch_bounds__(256) void kpackbA(
    const float* __restrict__ bx, const float* __restrict__ bh,
    const float* __restrict__ bm, const float* __restrict__ bo,
    float* __restrict__ bA)
{
  int idx = blockIdx.x * 256 + threadIdx.x;
  if (idx >= 1792) return;
  int ch = idx & 63, w = (idx >> 6) % 7, l = (idx >> 6) / 7;
  const float* bxl = bx + l * 448;
  const float* bhl = bh + l * 256;
  const float* bml = bm + l * 192;
  const float* bol = bo + l * 64;
  float v;
  if (w < 3)       v = bxl[w * 64 + ch] + bhl[w * 64 + ch];
  else if (w == 3) v = bxl[384 + ch] + bhl[192 + ch] + bol[ch];
  else             v = bxl[192 + (w - 4) * 64 + ch] + bml[(w - 4) * 64 + ch];
  bA[idx] = v;
}

extern "C" void kernel_launch(void* const* d_in, const int* in_sizes, int n_in,
                              void* d_out, int out_size, void* d_ws, size_t ws_size,
                              hipStream_t stream)
{
  (void)in_sizes; (void)n_in; (void)out_size;
  if (ws_size < WS_NEEDED_FLOATS * sizeof(float)) return;

  const float* x  = (const float*)d_in[0];
  const float* Wx = (const float*)d_in[3];
  const float* bx = (const float*)d_in[4];
  const float* Wh = (const float*)d_in[5];
  const float* bh = (const float*)d_in[6];
  const float* Wm = (const float*)d_in[7];
  const float* bm = (const float*)d_in[8];
  const float* Wo = (const float*)d_in[9];
  const float* bo = (const float*)d_in[10];
  const float* Wl = (const float*)d_in[11];
  const float* bl = (const float*)d_in[12];
  const float* Wd = (const float*)d_in[13];
  const float* bd = (const float*)d_in[14];
  float* ws  = (float*)d_ws;
  float* out = (float*)d_out;

  unsigned short* xpB   = (unsigned short*)(ws + OFF_XPB);
  unsigned short* outsB = (unsigned short*)(ws + OFF_OUTSB);
  unsigned short* hB    = (unsigned short*)(ws + OFF_HB);   // [2][4][...]
  unsigned short* mB    = (unsigned short*)(ws + OFF_MB);   // [2][...]
  float*          C     = ws + OFF_C;                       // [2][4][...]
  float*          M     = ws + OFF_M;                       // [2][...]
  unsigned short* wfA   = (unsigned short*)(ws + OFF_WFA);
  unsigned short* wfB   = (unsigned short*)(ws + OFF_WFB);
  unsigned short* wfD   = (unsigned short*)(ws + OFF_WFD);
  float*          bA    = ws + OFF_BA;

  kpackA<<<dim3(8064), 256, 0, stream>>>(Wx, Wh, Wm, wfA);
  kpackB<<<dim3(1280), 256, 0, stream>>>(Wo, Wl, wfB);
  kpackbA<<<dim3(7), 256, 0, stream>>>(bx, bh, bm, bo, bA);
  kprepw<<<dim3(144), 256, 0, stream>>>(Wd, wfD, 64, 64, 9);
  kpatch<<<dim3(80), 256, 0, stream>>>(x, xpB);
  // zero hB(2x), mB(2x), C(2x), M(2x) — contiguous [OFF_HB, OFF_WFA)
  hipMemsetAsync(ws + OFF_HB, 0, (OFF_WFA - OFF_HB) * sizeof(float), stream);

  for (int t = 0; t < T; ++t) {
    for (int l = 0; l < 4; ++l) {
      const int cell = t * 4 + l;
      const int pt = t & 1, pm = cell & 1;
      const unsigned short* in0; long ibs;
      if (l == 0) {
        if (t < INLEN) { in0 = xpB + (long)t * 65536; ibs = 655360; }
        else           { in0 = outsB + (long)(t - 1) * 524288; ibs = 65536; }
      } else {
        in0 = hB + ((long)pt * 4 + (l - 1)) * 524288; ibs = 65536;
      }
      kcell<<<dim3(256), 448, 0, stream>>>(
          in0, ibs,
          hB + ((long)(pt ^ 1) * 4 + l) * 524288,   // hRead  (t-1)
          hB + ((long)pt * 4 + l) * 524288,         // hWrite (t)
          mB + (long)(pm ^ 1) * 524288,             // mBr
          mB + (long)pm * 524288,                   // mBw
          C + ((long)(pt ^ 1) * 4 + l) * 524288,    // Cprev
          C + ((long)pt * 4 + l) * 524288,          // Cnext
          M + (long)(pm ^ 1) * 524288,              // Mprev
          M + (long)pm * 524288,                    // Mnext
          wfA + (long)l * 516096, wfB + (long)l * 81920,
          bA + l * 448, bl + l * 64,
          outsB + (long)t * 524288, (l == 3) ? 1 : 0);
    }
  }
  kconv_final<<<dim3(152, 4), 256, 0, stream>>>(outsB, wfD, bd, out);
}

// Round 9
// 2521.583 us; speedup vs baseline: 3.2244x; 1.3918x over previous
//
#include <hip/hip_runtime.h>
#include <hip/hip_bf16.h>

// ---------------------------------------------------------------------------
// PredRNN (patched) — R9: R3 champion + coalesced bf16 state stores.
// Changes vs R3 (2654us):
//  1. memB ping-pong replaces the separate m buffer: kcellA reads m-input from
//     memBprev[ch 64:128), writes memBnext; mBw scalar stores eliminated.
//  2. kcellA epilogue: c/m bf16 written to a swizzled LDS tile, then flushed
//     as coalesced uint4 (was: 2-byte stores at 256B lane stride).
//  3. kcellB gate2 epilogue: same LDS-tile + uint4 flush for h/outs.
// Everything else (phase structure, K-loops, packers, final conv) R3-verbatim.
// ---------------------------------------------------------------------------

typedef __bf16 bf16x8 __attribute__((ext_vector_type(8)));
typedef float f32x4 __attribute__((ext_vector_type(4)));

namespace {
constexpr int  T     = 19;
constexpr int  INLEN = 10;

// workspace offsets (in floats)
constexpr long OFF_XPB   = 0;            // bf16 [8][10][1024][64]
constexpr long OFF_OUTSB = 2621440;      // bf16 [19][8][1024][64]
constexpr long OFF_HB    = 7602176;      // bf16 [4][8][1024][64]
constexpr long OFF_C     = 9699328;      // fp32 [4][8][64][1024]
constexpr long OFF_M     = 11796480;     // fp32 [8][64][1024]
constexpr long OFF_MEMB  = 12320768;     // bf16 2x [8][1024][128] (ping-pong)
constexpr long OFF_OP    = 13369344;     // fp32 [8][64][1024]
constexpr long OFF_WFA   = 13893632;     // bf16 4 x 516096
constexpr long OFF_WFB   = 14925824;     // bf16 4 x 81920
constexpr long OFF_WFD   = 15089664;     // bf16 36864
constexpr long OFF_BA    = 15108096;     // fp32 4 x 448
constexpr long WS_NEEDED_FLOATS = 15109888;
}

__device__ __forceinline__ float sigf(float x)     { return 1.f / (1.f + __expf(-x)); }
__device__ __forceinline__ float tanhfast(float x) { return 2.f / (1.f + __expf(-2.f * x)) - 1.f; }
__device__ __forceinline__ unsigned short f2b(float f) {
  __hip_bfloat16 h = __float2bfloat16(f);
  return __builtin_bit_cast(unsigned short, h);
}
__device__ __forceinline__ f32x4 mfma16(bf16x8 a, bf16x8 b, f32x4 c) {
  return __builtin_amdgcn_mfma_f32_16x16x32_bf16(a, b, c, 0, 0, 0);
}

// ---------------------------------------------------------------------------
// kcellA: grid (8, 32), 448 threads (7 waves). R3-verbatim K-loop.
// Wave w co-tile: w0=i w1=f w2=g w3=o (inputs x,h) ; w4=i' w5=f' w6=g' (x,m).
// ---------------------------------------------------------------------------
__global__ __launch_bounds__(448) void kcellA(
    const unsigned short* __restrict__ in0, long in0bs,
    const unsigned short* __restrict__ hB,
    const unsigned short* __restrict__ memBprev,
    const unsigned short* __restrict__ wfA,
    const float* __restrict__ bA,
    float* __restrict__ C, float* __restrict__ M,
    unsigned short* __restrict__ memBnext,
    float* __restrict__ op)
{
  __shared__ __align__(16) char smem[65536];
  unsigned short* sIn = (unsigned short*)smem;   // 3 inputs x 102 slots x 64ci
  float* sEx = (float*)smem;                     // 7 slabs x 2048 fp32
  unsigned short* sT = (unsigned short*)(smem + 57344);  // 32px x 128ch tile

  const int b = blockIdx.x, r0 = blockIdx.y, tid = threadIdx.x;
  const unsigned short* base0 = in0 + (long)b * in0bs;
  const unsigned short* base1 = hB + ((long)b << 16);
  const unsigned short* base2 = memBprev + ((long)b << 17);

  // stage 3 input row-strips (rows r0-1..r0+1, cols -1..32, 64 ci, swizzled)
  for (int s = tid; s < 3 * 816; s += 448) {
    int inp = s / 816, rem = s - inp * 816;
    int slot = rem >> 3, cg = rem & 7;
    int rr = slot / 34, cl = slot - rr * 34;
    int gr = r0 - 1 + rr, gc = cl - 1;
    uint4 v = make_uint4(0u, 0u, 0u, 0u);
    if ((unsigned)gr < 32u && (unsigned)gc < 32u) {
      if (inp == 0)      v = *(const uint4*)(base0 + ((long)(gr * 32 + gc) << 6) + cg * 8);
      else if (inp == 1) v = *(const uint4*)(base1 + ((long)(gr * 32 + gc) << 6) + cg * 8);
      else               v = *(const uint4*)(base2 + ((long)(gr * 32 + gc) << 7) + 64 + cg * 8);
    }
    *(uint4*)(sIn + inp * 6528 + slot * 64 + ((cg ^ (slot & 7)) * 8)) = v;
  }
  __syncthreads();

  const int w = tid >> 6, lane = tid & 63, q = lane >> 4, n16 = lane & 15;
  f32x4 acc[4][2];
  #pragma unroll
  for (int i = 0; i < 4; ++i) { acc[i][0] = (f32x4){0,0,0,0}; acc[i][1] = (f32x4){0,0,0,0}; }

  const unsigned short* sb1 = sIn + ((w < 4) ? 6528 : 13056);
  const unsigned short* wbase = wfA + (long)w * 73728;

  #pragma unroll
  for (int p = 0; p < 2; ++p) {
    const unsigned short* sb = p ? sb1 : sIn;
    #pragma unroll
    for (int tap = 0; tap < 9; ++tap) {
      const int dy = tap / 3, dx = tap - dy * 3;
      #pragma unroll
      for (int cc = 0; cc < 2; ++cc) {
        const unsigned short* wp = wbase + (long)(((p * 9 + tap) * 2 + cc) * 4) * 512 + lane * 8;
        bf16x8 a0 = *(const bf16x8*)(wp);
        bf16x8 a1 = *(const bf16x8*)(wp + 512);
        bf16x8 a2 = *(const bf16x8*)(wp + 1024);
        bf16x8 a3 = *(const bf16x8*)(wp + 1536);
        const int g = cc * 4 + q;
        bf16x8 bf0, bf1;
        { int slot = dy * 34 + n16 + dx;
          bf0 = *(const bf16x8*)(sb + slot * 64 + ((g ^ (slot & 7)) * 8)); }
        { int slot = dy * 34 + 16 + n16 + dx;
          bf1 = *(const bf16x8*)(sb + slot * 64 + ((g ^ (slot & 7)) * 8)); }
        acc[0][0] = mfma16(a0, bf0, acc[0][0]); acc[0][1] = mfma16(a0, bf1, acc[0][1]);
        acc[1][0] = mfma16(a1, bf0, acc[1][0]); acc[1][1] = mfma16(a1, bf1, acc[1][1]);
        acc[2][0] = mfma16(a2, bf0, acc[2][0]); acc[2][1] = mfma16(a2, bf1, acc[2][1]);
        acc[3][0] = mfma16(a3, bf0, acc[3][0]); acc[3][1] = mfma16(a3, bf1, acc[3][1]);
      }
    }
  }

  __syncthreads();   // all waves done reading sIn before slab overwrite
  #pragma unroll
  for (int i = 0; i < 4; ++i)
    #pragma unroll
    for (int j = 0; j < 2; ++j)
      #pragma unroll
      for (int r = 0; r < 4; ++r)
        sEx[w * 2048 + (i * 16 + q * 4 + r) * 32 + (j * 16 + n16)] = acc[i][j][r];
  __syncthreads();

  // gate1 epilogue: state update + bf16 tile in LDS
  for (int idx = tid; idx < 2048; idx += 448) {
    const int ch = idx >> 5, pxl = idx & 31;
    const int pxg = r0 * 32 + pxl;
    float iv = sEx[idx]         + bA[ch];
    float fv = sEx[2048 + idx]  + bA[64 + ch];
    float gv = sEx[4096 + idx]  + bA[128 + ch];
    float ov = sEx[6144 + idx]  + bA[192 + ch];
    float i2 = sEx[8192 + idx]  + bA[256 + ch];
    float f2 = sEx[10240 + idx] + bA[320 + ch];
    float g2 = sEx[12288 + idx] + bA[384 + ch];
    const long cmo = ((long)b * 64 + ch) * 1024 + pxg;
    float cn = sigf(fv) * C[cmo] + sigf(iv) * tanhfast(gv);
    float mn = sigf(f2) * M[cmo] + sigf(i2) * tanhfast(g2);
    C[cmo] = cn; M[cmo] = mn; op[cmo] = ov;
    sT[pxl * 128 + (((ch >> 3) ^ (pxl & 7)) * 8) + (ch & 7)] = f2b(cn);
    const int chm = 64 + ch;
    sT[pxl * 128 + (((chm >> 3) ^ (pxl & 7)) * 8) + (chm & 7)] = f2b(mn);
  }
  __syncthreads();

  // coalesced flush: 512 uint4 (32px x 16 ch-groups)
  for (int u = tid; u < 512; u += 448) {
    const int px = u >> 4, cg = u & 15;
    uint4 v = *(const uint4*)(sT + px * 128 + ((cg ^ (px & 7)) * 8));
    *(uint4*)(memBnext + (((long)b * 1024 + r0 * 32 + px) << 7) + cg * 8) = v;
  }
}

// ---------------------------------------------------------------------------
// kcellB: grid (8, 32), 512 threads (8 waves). R3-verbatim K-split.
// 40 K-steps (36 convO + 4 convL) split 5/wave; LDS reduce; gate2 epilogue
// via LDS tile + coalesced flush.
// ---------------------------------------------------------------------------
__global__ __launch_bounds__(512) void kcellB(
    const unsigned short* __restrict__ memB,
    const unsigned short* __restrict__ wfBl,
    const float* __restrict__ op, const float* __restrict__ bl,
    unsigned short* __restrict__ hBw, unsigned short* __restrict__ outsBt,
    int writeOuts)
{
  __shared__ __align__(16) char smem[77824];
  unsigned short* sIn = (unsigned short*)smem;   // 102 slots x 128 ci
  float* sEx = (float*)smem;                     // 9 slabs x 2048 fp32
  unsigned short* sT = (unsigned short*)(smem + 73728);  // 32px x 64ch tile

  const int b = blockIdx.x, r0 = blockIdx.y, tid = threadIdx.x;
  const unsigned short* bp = memB + ((long)b << 17);
  for (int s = tid; s < 102 * 16; s += 512) {
    int slot = s >> 4, cg = s & 15;
    int rr = slot / 34, cl = slot - rr * 34;
    int gr = r0 - 1 + rr, gc = cl - 1;
    uint4 v = make_uint4(0u, 0u, 0u, 0u);
    if ((unsigned)gr < 32u && (unsigned)gc < 32u)
      v = *(const uint4*)(bp + ((long)(gr * 32 + gc) << 7) + cg * 8);
    *(uint4*)(sIn + slot * 128 + ((cg ^ (slot & 7)) * 8)) = v;
  }
  __syncthreads();

  const int w = tid >> 6, lane = tid & 63, q = lane >> 4, n16 = lane & 15;
  f32x4 accO[4][2], accL[4][2];
  #pragma unroll
  for (int f = 0; f < 4; ++f) {
    accO[f][0] = (f32x4){0.f,0.f,0.f,0.f}; accO[f][1] = (f32x4){0.f,0.f,0.f,0.f};
    accL[f][0] = (f32x4){0.f,0.f,0.f,0.f}; accL[f][1] = (f32x4){0.f,0.f,0.f,0.f};
  }

  #pragma unroll
  for (int s5 = 0; s5 < 5; ++s5) {
    const int s = w * 5 + s5;
    const bool isL = (s >= 36);
    const int tap = isL ? 4 : (s >> 2);
    const int cc  = isL ? (s - 36) : (s & 3);
    const int dy = tap / 3, dx = tap - dy * 3;
    const unsigned short* wp = wfBl + (long)s * 2048 + lane * 8;
    bf16x8 a0 = *(const bf16x8*)(wp);
    bf16x8 a1 = *(const bf16x8*)(wp + 512);
    bf16x8 a2 = *(const bf16x8*)(wp + 1024);
    bf16x8 a3 = *(const bf16x8*)(wp + 1536);
    const int g = cc * 4 + q;
    bf16x8 bf0, bf1;
    { int slot = dy * 34 + n16 + dx;
      bf0 = *(const bf16x8*)(sIn + slot * 128 + ((g ^ (slot & 7)) * 8)); }
    { int slot = dy * 34 + 16 + n16 + dx;
      bf1 = *(const bf16x8*)(sIn + slot * 128 + ((g ^ (slot & 7)) * 8)); }
    if (isL) {
      accL[0][0] = mfma16(a0, bf0, accL[0][0]); accL[0][1] = mfma16(a0, bf1, accL[0][1]);
      accL[1][0] = mfma16(a1, bf0, accL[1][0]); accL[1][1] = mfma16(a1, bf1, accL[1][1]);
      accL[2][0] = mfma16(a2, bf0, accL[2][0]); accL[2][1] = mfma16(a2, bf1, accL[2][1]);
      accL[3][0] = mfma16(a3, bf0, accL[3][0]); accL[3][1] = mfma16(a3, bf1, accL[3][1]);
    } else {
      accO[0][0] = mfma16(a0, bf0, accO[0][0]); accO[0][1] = mfma16(a0, bf1, accO[0][1]);
      accO[1][0] = mfma16(a1, bf0, accO[1][0]); accO[1][1] = mfma16(a1, bf1, accO[1][1]);
      accO[2][0] = mfma16(a2, bf0, accO[2][0]); accO[2][1] = mfma16(a2, bf1, accO[2][1]);
      accO[3][0] = mfma16(a3, bf0, accO[3][0]); accO[3][1] = mfma16(a3, bf1, accO[3][1]);
    }
  }

  __syncthreads();
  #pragma unroll
  for (int i = 0; i < 4; ++i)
    #pragma unroll
    for (int j = 0; j < 2; ++j)
      #pragma unroll
      for (int r = 0; r < 4; ++r)
        sEx[w * 2048 + (i * 16 + q * 4 + r) * 32 + (j * 16 + n16)] = accO[i][j][r];
  if (w == 7) {
    #pragma unroll
    for (int i = 0; i < 4; ++i)
      #pragma unroll
      for (int j = 0; j < 2; ++j)
        #pragma unroll
        for (int r = 0; r < 4; ++r)
          sEx[16384 + (i * 16 + q * 4 + r) * 32 + (j * 16 + n16)] = accL[i][j][r];
  }
  __syncthreads();

  for (int idx = tid; idx < 2048; idx += 512) {
    const int ch = idx >> 5, pxl = idx & 31;
    const int pxg = r0 * 32 + pxl;
    float o = op[((long)b * 64 + ch) * 1024 + pxg];
    #pragma unroll
    for (int ww = 0; ww < 8; ++ww) o += sEx[ww * 2048 + idx];
    float l = sEx[16384 + idx] + bl[ch];
    sT[pxl * 64 + (((ch >> 3) ^ (pxl & 7)) * 8) + (ch & 7)] = f2b(sigf(o) * tanhfast(l));
  }
  __syncthreads();

  for (int u = tid; u < 256; u += 512) {
    const int px = u >> 3, cg = u & 7;
    uint4 v = *(const uint4*)(sT + px * 64 + ((cg ^ (px & 7)) * 8));
    const long base = (((long)b * 1024 + r0 * 32 + px) << 6) + cg * 8;
    *(uint4*)(hBw + base) = v;
    if (writeOuts) *(uint4*)(outsBt + base) = v;
  }
}

// ---------------------------------------------------------------------------
// Final conv machinery (verbatim R2/R3, proven correct)
// ---------------------------------------------------------------------------
__device__ __forceinline__ void conv3_acc(
    const unsigned short* __restrict__ ip, int ciStride, int ciOff,
    const unsigned short* __restrict__ wf, int ncc, int ccoff,
    unsigned short* sIn, f32x4 (&acc)[4][4])
{
  const int tid = threadIdx.x;
  const int r0  = (int)blockIdx.y * 8;
  for (int s = tid; s < 2720; s += 256) {
    int slot = s >> 3, cg = s & 7;
    int rr = slot / 34, cl = slot - rr * 34;
    int gr = r0 - 1 + rr, gc = cl - 1;
    uint4 v = make_uint4(0u, 0u, 0u, 0u);
    if ((unsigned)gr < 32u && (unsigned)gc < 32u)
      v = *(const uint4*)(ip + (long)(gr * 32 + gc) * ciStride + ciOff + cg * 8);
    *(uint4*)(sIn + slot * 64 + ((cg ^ (slot & 7)) * 8)) = v;
  }
  __syncthreads();
  const int lane = tid & 63, w = tid >> 6;
  const int q = lane >> 4, n16 = lane & 15;
  #pragma unroll
  for (int i = 0; i < 4; ++i)
    #pragma unroll
    for (int j = 0; j < 4; ++j)
      acc[i][j] = (f32x4){0.f, 0.f, 0.f, 0.f};
  #pragma unroll
  for (int tap = 0; tap < 9; ++tap) {
    const int dy = tap / 3, dx = tap - dy * 3;
    #pragma unroll
    for (int cc = 0; cc < 2; ++cc) {
      const unsigned short* wp = wf + (long)(tap * ncc + ccoff + cc) * 2048 + lane * 8;
      bf16x8 a0 = *(const bf16x8*)(wp);
      bf16x8 a1 = *(const bf16x8*)(wp + 512);
      bf16x8 a2 = *(const bf16x8*)(wp + 1024);
      bf16x8 a3 = *(const bf16x8*)(wp + 1536);
      const int cs = cc * 4 + q;
      bf16x8 bfr[4];
      #pragma unroll
      for (int pf = 0; pf < 4; ++pf) {
        int slot = (w * 2 + (pf >> 1) + dy) * 34 + (pf & 1) * 16 + dx + n16;
        bfr[pf] = *(const bf16x8*)(sIn + slot * 64 + ((cs ^ (slot & 7)) * 8));
      }
      #pragma unroll
      for (int j = 0; j < 4; ++j) {
        acc[0][j] = mfma16(a0, bfr[j], acc[0][j]);
        acc[1][j] = mfma16(a1, bfr[j], acc[1][j]);
        acc[2][j] = mfma16(a2, bfr[j], acc[2][j]);
        acc[3][j] = mfma16(a3, bfr[j], acc[3][j]);
      }
    }
  }
}

__global__ __launch_bounds__(256) void kconv_final(
    const unsigned short* __restrict__ outsB,
    const unsigned short* __restrict__ wdf, const float* __restrict__ bd,
    float* __restrict__ dout)
{
  __shared__ __align__(16) unsigned short sIn[21760];
  const int img = blockIdx.x;
  const int b = img / 19, t = img - b * 19;
  f32x4 acc[4][4];
  conv3_acc(outsB + ((long)t * 8 + b) * 65536, 64, 0, wdf, 2, 0, sIn, acc);
  const int tid = threadIdx.x;
  const int lane = tid & 63, w = tid >> 6;
  const int q = lane >> 4, n16 = lane & 15;
  const int r0 = (int)blockIdx.y * 8;
  float* ob = dout + (long)img * 65536;
  #pragma unroll
  for (int i = 0; i < 4; ++i) {
    #pragma unroll
    for (int r = 0; r < 4; ++r) {
      const int co = i * 16 + q * 4 + r;
      const float bv = bd[co];
      #pragma unroll
      for (int j = 0; j < 4; ++j) {
        int row = r0 + w * 2 + (j >> 1);
        int col = (j & 1) * 16 + n16;
        ob[((co >> 3) * 32 + row) * 256 + (co & 7) * 32 + col] = sigf(acc[i][j][r] + bv);
      }
    }
  }
}

// patch division -> bf16 channels-last [b*10+t][1024][64]; grid (80)
__global__ __launch_bounds__(256) void kpatch(const float* __restrict__ x,
                                              unsigned short* __restrict__ xpB)
{
  __shared__ __align__(16) unsigned short sT[2048];
  const int img = blockIdx.x, tid = threadIdx.x;
  const float* xi = x + (long)img * 65536;
  unsigned short* xo = xpB + (long)img * 65536;
  for (int p = 0; p < 32; ++p) {
    __syncthreads();
    int ch = tid >> 2, q0 = (tid & 3) * 8;
    const float* s = xi + ((ch >> 3) * 32 + p) * 256 + (ch & 7) * 32 + q0;
    float4 v0 = *(const float4*)s, v1 = *(const float4*)(s + 4);
    float vv[8] = {v0.x, v0.y, v0.z, v0.w, v1.x, v1.y, v1.z, v1.w};
    #pragma unroll
    for (int k = 0; k < 8; ++k) {
      int qq = q0 + k;
      sT[qq * 64 + (((ch >> 3) ^ (qq & 7)) * 8) + (ch & 7)] = f2b(vv[k]);
    }
    __syncthreads();
    int q = tid >> 3, cg = tid & 7;
    uint4 v = *(const uint4*)(sT + q * 64 + ((cg ^ (q & 7)) * 8));
    *(uint4*)(xo + (long)(p * 32 + q) * 64 + cg * 8) = v;
  }
}

// weight fragment packer (used for Wd only)
__global__ __launch_bounds__(256) void kprepw(const float* __restrict__ src,
                                              unsigned short* __restrict__ dst,
                                              int Cout, int Cin, int KK)
{
  long n = (long)Cout * Cin * KK;
  long idx = (long)blockIdx.x * 256 + threadIdx.x;
  if (idx >= n) return;
  int ncc = Cin >> 5;
  long tmp = idx >> 3; int e = (int)(idx & 7);
  int lane = (int)(tmp & 63); tmp >>= 6;
  int cf = (int)(tmp & 3); tmp >>= 2;
  int cc = (int)(tmp % ncc); tmp /= ncc;
  int tap = (int)(tmp % KK); int chunk = (int)(tmp / KK);
  int co = chunk * 64 + cf * 16 + (lane & 15);
  int ci = cc * 32 + (lane >> 4) * 8 + e;
  dst[idx] = f2b(src[((long)co * Cin + ci) * KK + tap]);
}

// pack fused stage-1 weights (R3 layout): [l][w][p][tap][cc][frag][lane][8]
__global__ __launch_bounds__(256) void kpackA(
    const float* __restrict__ Wx, const float* __restrict__ Wh,
    const float* __restrict__ Wm, unsigned short* __restrict__ wfA)
{
  long idx = (long)blockIdx.x * 256 + threadIdx.x;
  if (idx >= 2064384) return;
  int e = (int)(idx & 7);
  long t = idx >> 3;
  int lane = (int)(t & 63); t >>= 6;
  int frag = (int)(t & 3);  t >>= 2;
  int cc   = (int)(t & 1);  t >>= 1;
  int tap  = (int)(t % 9);  t /= 9;
  int p    = (int)(t & 1);  t >>= 1;
  int w    = (int)(t % 7);
  int l    = (int)(t / 7);
  int co = frag * 16 + (lane & 15);
  int ci = cc * 32 + (lane >> 4) * 8 + e;
  const float* src; int row;
  if (w < 4) {
    if (p == 0) { src = Wx + (long)l * 258048; row = (w == 3 ? 384 : w * 64) + co; }
    else        { src = Wh + (long)l * 147456; row = (w == 3 ? 192 : w * 64) + co; }
  } else {
    if (p == 0) { src = Wx + (long)l * 258048; row = 192 + (w - 4) * 64 + co; }
    else        { src = Wm + (long)l * 110592; row = (w - 4) * 64 + co; }
  }
  wfA[idx] = f2b(src[((long)row * 64 + ci) * 9 + tap]);
}

// pack convO/convL step-ordered weights (R3 layout): [l][s 0..39][frag][lane][8]
__global__ __launch_bounds__(256) void kpackB(
    const float* __restrict__ Wo, const float* __restrict__ Wl,
    unsigned short* __restrict__ wfB)
{
  long idx = (long)blockIdx.x * 256 + threadIdx.x;
  if (idx >= 327680) return;
  int e = (int)(idx & 7);
  long t = idx >> 3;
  int lane = (int)(t & 63); t >>= 6;
  int frag = (int)(t & 3);  t >>= 2;
  int s    = (int)(t % 40);
  int l    = (int)(t / 40);
  int co = frag * 16 + (lane & 15);
  float v;
  if (s < 36) {
    int tap = s >> 2, cc = s & 3;
    int ci = cc * 32 + (lane >> 4) * 8 + e;
    v = Wo[(long)l * 73728 + ((long)co * 128 + ci) * 9 + tap];
  } else {
    int cc = s - 36;
    int ci = cc * 32 + (lane >> 4) * 8 + e;
    v = Wl[(long)l * 8192 + (long)co * 128 + ci];
  }
  wfB[idx] = f2b(v);
}

// pre-summed gate biases: [l][slot i,f,g,o(+bo),i2,f2,g2][64]
__global__ __launch_bounds__(256) void kpackbA(
    const float* __restrict__ bx, const float* __restrict__ bh,
    const float* __restrict__ bm, const float* __restrict__ bo,
    float* __restrict__ bA)
{
  int idx = blockIdx.x * 256 + threadIdx.x;
  if (idx >= 1792) return;
  int ch = idx & 63, w = (idx >> 6) % 7, l = (idx >> 6) / 7;
  const float* bxl = bx + l * 448;
  const float* bhl = bh + l * 256;
  const float* bml = bm + l * 192;
  const float* bol = bo + l * 64;
  float v;
  if (w < 3)       v = bxl[w * 64 + ch] + bhl[w * 64 + ch];
  else if (w == 3) v = bxl[384 + ch] + bhl[192 + ch] + bol[ch];
  else             v = bxl[192 + (w - 4) * 64 + ch] + bml[(w - 4) * 64 + ch];
  bA[idx] = v;
}

extern "C" void kernel_launch(void* const* d_in, const int* in_sizes, int n_in,
                              void* d_out, int out_size, void* d_ws, size_t ws_size,
                              hipStream_t stream)
{
  (void)in_sizes; (void)n_in; (void)out_size;
  if (ws_size < WS_NEEDED_FLOATS * sizeof(float)) return;

  const float* x  = (const float*)d_in[0];
  const float* Wx = (const float*)d_in[3];
  const float* bx = (const float*)d_in[4];
  const float* Wh = (const float*)d_in[5];
  const float* bh = (const float*)d_in[6];
  const float* Wm = (const float*)d_in[7];
  const float* bm = (const float*)d_in[8];
  const float* Wo = (const float*)d_in[9];
  const float* bo = (const float*)d_in[10];
  const float* Wl = (const float*)d_in[11];
  const float* bl = (const float*)d_in[12];
  const float* Wd = (const float*)d_in[13];
  const float* bd = (const float*)d_in[14];
  float* ws  = (float*)d_ws;
  float* out = (float*)d_out;

  unsigned short* xpB   = (unsigned short*)(ws + OFF_XPB);
  unsigned short* outsB = (unsigned short*)(ws + OFF_OUTSB);
  unsigned short* hB    = (unsigned short*)(ws + OFF_HB);
  float*          C     = ws + OFF_C;
  float*          M     = ws + OFF_M;
  unsigned short* memB0 = (unsigned short*)(ws + OFF_MEMB);
  unsigned short* memB1 = memB0 + 1048576;
  float*          OP    = ws + OFF_OP;
  unsigned short* wfA   = (unsigned short*)(ws + OFF_WFA);
  unsigned short* wfB   = (unsigned short*)(ws + OFF_WFB);
  unsigned short* wfD   = (unsigned short*)(ws + OFF_WFD);
  float*          bA    = ws + OFF_BA;

  kpackA<<<dim3(8064), 256, 0, stream>>>(Wx, Wh, Wm, wfA);
  kpackB<<<dim3(1280), 256, 0, stream>>>(Wo, Wl, wfB);
  kpackbA<<<dim3(7), 256, 0, stream>>>(bx, bh, bm, bo, bA);
  kprepw<<<dim3(144), 256, 0, stream>>>(Wd, wfD, 64, 64, 9);
  kpatch<<<dim3(80), 256, 0, stream>>>(x, xpB);
  // zero hB, C, M, memB(2x), OP (contiguous region)
  hipMemsetAsync(ws + OFF_HB, 0, (OFF_WFA - OFF_HB) * sizeof(float), stream);

  for (int t = 0; t < T; ++t) {
    for (int l = 0; l < 4; ++l) {
      const int cell = t * 4 + l;
      const unsigned short* in0; long ibs;
      if (l == 0) {
        if (t < INLEN) { in0 = xpB + (long)t * 65536; ibs = 655360; }
        else           { in0 = outsB + (long)(t - 1) * 524288; ibs = 65536; }
      } else {
        in0 = hB + (long)(l - 1) * 524288; ibs = 65536;
      }
      const unsigned short* mprev = (cell & 1) ? memB1 : memB0;
      unsigned short*       mnext = (cell & 1) ? memB0 : memB1;
      kcellA<<<dim3(8, 32), 448, 0, stream>>>(
          in0, ibs, hB + (long)l * 524288, mprev,
          wfA + (long)l * 516096, bA + l * 448,
          C + (long)l * 524288, M, mnext, OP);
      kcellB<<<dim3(8, 32), 512, 0, stream>>>(
          mnext, wfB + (long)l * 81920, OP, bl + l * 64,
          hB + (long)l * 524288, outsB + (long)t * 524288, (l == 3) ? 1 : 0);
    }
  }
  kconv_final<<<dim3(152, 4), 256, 0, stream>>>(outsB, wfD, bd, out);
}